// Round 12
// baseline (278.476 us; speedup 1.0000x reference)
//
#include <hip/hip_runtime.h>
#include <math.h>

typedef unsigned short u16;
typedef __attribute__((ext_vector_type(4))) float f32x4;
typedef __attribute__((ext_vector_type(16))) float f32x16;
typedef __attribute__((ext_vector_type(8))) short bf16x8;

#define B_ 2
#define S_ 2048
#define DM 1024
#define H_ 16
#define AD 64
#define ME 4194304  // elems in one 4096x1024 matrix
#define SC 0.18033688011112042f  // 0.125 * log2(e), folded into Q
#define SMAX 12.0f               // static softmax max: |logit*log2e| <= 11.54

#define GLL(g, s) __builtin_amdgcn_global_load_lds( \
  (const __attribute__((address_space(1))) void*)(g), \
  (__attribute__((address_space(3))) void*)(s), 16, 0, 0)

__device__ inline u16 f2bf(float f) {
  union { float f; unsigned u; } v; v.f = f;
  unsigned r = v.u + 0x7fffu + ((v.u >> 16) & 1u);
  return (u16)(r >> 16);
}

__device__ inline unsigned cvt_pk_bf16(float lo, float hi) {
  unsigned r;
  asm("v_cvt_pk_bf16_f32 %0, %1, %2" : "=v"(r) : "v"(lo), "v"(hi));
  return r;
}

// tanh(x) = 1 - 2/(exp(2x)+1); exp2/rcp HW approx, |err| ~1e-6 << 2e-2 thr
__device__ inline float fast_tanh(float x) {
  float e = __builtin_amdgcn_exp2f(x * 2.885390081777927f);  // exp(2x)
  return 1.f - 2.f * __builtin_amdgcn_rcpf(e + 1.f);
}

// ------- prep: W transpose+cvt (z=0..3), states cvt (z=4), counter zero -----
__global__ void prep(const float* __restrict__ Wq, const float* __restrict__ Wk,
                     const float* __restrict__ Wv, const float* __restrict__ Wo,
                     u16* __restrict__ Wt, const float* __restrict__ states,
                     u16* __restrict__ sbf, int* __restrict__ cnt) {
  __shared__ float t[32][33];
  const int z = blockIdx.z;
  const int tx = threadIdx.x, ty = threadIdx.y;
  if (z < 4) {
    const float* W = (z == 0) ? Wq : (z == 1) ? Wk : (z == 2) ? Wv : Wo;
    u16* out = Wt + (size_t)z * DM * DM;
    int n0 = blockIdx.x * 32, k0 = blockIdx.y * 32;
    t[ty][tx] = W[(k0 + ty) * DM + n0 + tx];
    __syncthreads();
    out[(n0 + ty) * DM + k0 + tx] = f2bf(t[tx][ty]);
  } else {
    const int lin = blockIdx.y * 32 + blockIdx.x;
    const int tl = ty * 32 + tx;
    const int i = (lin * 1024 + tl) * 4;
    float4 a = *(const float4*)(states + i);
    ushort4 o;
    o.x = f2bf(a.x); o.y = f2bf(a.y); o.z = f2bf(a.z); o.w = f2bf(a.w);
    *(ushort4*)&sbf[i] = o;
    if (lin == 0 && tl < 512) cnt[tl] = 0;  // combine arrival counters
  }
}

// ---------------- fused QKV projection GEMM + tanh (R9-proven + T1 swizzle) -
__global__ __launch_bounds__(256) void qkv_gemm(
    const u16* __restrict__ A, const u16* __restrict__ Wt,
    const float* __restrict__ bq, const float* __restrict__ bk, const float* __restrict__ bv,
    u16* __restrict__ Qw, u16* __restrict__ Kw, u16* __restrict__ Vtw) {
  __shared__ __attribute__((aligned(16))) u16 lA[128 * 32];
  __shared__ __attribute__((aligned(16))) u16 lB[128 * 32];
  const int z = blockIdx.z;
  const u16* Bt = Wt + (size_t)z * DM * DM;
  const int lin = blockIdx.y * 8 + blockIdx.x;     // hw dispatch order, x fastest
  const int tile = (lin & 7) * 32 + (lin >> 3);    // XCD-chunked remap
  const int m0 = (tile >> 3) * 128, n0 = (tile & 7) * 128;
  const int tid = threadIdx.x;
  const int wid = tid >> 6, l = tid & 63;
  const int lr = l & 15, lk = l >> 4;
  const int wm = (wid >> 1) * 64, wn = (wid & 1) * 64;
  const int srow = wid * 32 + (l >> 2);
  const int scol = (l & 3) * 8;

  f32x4 acc[4][4] = {};

  for (int k0 = 0; k0 < DM; k0 += 32) {
    const u16* gA = &A[(size_t)(m0 + srow) * DM + k0 + scol];
    const u16* gB = &Bt[(size_t)(n0 + srow) * DM + k0 + scol];
    GLL(gA,           lA + wid * 1024);
    GLL(gA + 16 * DM, lA + wid * 1024 + 512);
    GLL(gB,           lB + wid * 1024);
    GLL(gB + 16 * DM, lB + wid * 1024 + 512);
    __syncthreads();
    bf16x8 af[4], bfr[4];
#pragma unroll
    for (int g = 0; g < 4; ++g) {
      af[g]  = *(const bf16x8*)&lA[(wm + g * 16 + lr) * 32 + lk * 8];
      bfr[g] = *(const bf16x8*)&lB[(wn + g * 16 + lr) * 32 + lk * 8];
    }
#pragma unroll
    for (int mg = 0; mg < 4; ++mg)
#pragma unroll
      for (int ng = 0; ng < 4; ++ng)
        acc[mg][ng] = __builtin_amdgcn_mfma_f32_16x16x32_bf16(af[mg], bfr[ng], acc[mg][ng], 0, 0, 0);
    __syncthreads();
  }

  const float* bias = (z == 0) ? bq : (z == 1) ? bk : bv;
#pragma unroll
  for (int mg = 0; mg < 4; ++mg)
#pragma unroll
    for (int ng = 0; ng < 4; ++ng)
#pragma unroll
      for (int r = 0; r < 4; ++r) {
        int m = m0 + wm + mg * 16 + lk * 4 + r;
        int n = n0 + wn + ng * 16 + lr;
        float v = fast_tanh(acc[mg][ng][r] + bias[n]);
        if (z == 0) v *= SC;  // fold softmax scale into Q
        u16 h16 = f2bf(v);
        int bb = m >> 11, s = m & 2047, hh = n >> 6, d = n & 63;
        if (z == 2) Vtw[((size_t)(bb * H_ + hh) * AD + d) * S_ + s] = h16;
        else ((z == 0) ? Qw : Kw)[((size_t)(bb * H_ + hh) * S_ + s) * AD + d] = h16;
      }
}

// ---------------- output projection GEMM + tanh (R9-proven + T1 swizzle) ----
__global__ __launch_bounds__(256) void out_gemm(
    const u16* __restrict__ A, const u16* __restrict__ Bt,
    const float* __restrict__ bo, float* __restrict__ out) {
  __shared__ __attribute__((aligned(16))) u16 lA[128 * 32];
  __shared__ __attribute__((aligned(16))) u16 lB[128 * 32];
  const int lin = blockIdx.y * 8 + blockIdx.x;
  const int tile = (lin & 7) * 32 + (lin >> 3);
  const int m0 = (tile >> 3) * 128, n0 = (tile & 7) * 128;
  const int tid = threadIdx.x;
  const int wid = tid >> 6, l = tid & 63;
  const int lr = l & 15, lk = l >> 4;
  const int wm = (wid >> 1) * 64, wn = (wid & 1) * 64;
  const int srow = wid * 32 + (l >> 2);
  const int scol = (l & 3) * 8;

  f32x4 acc[4][4] = {};

  for (int k0 = 0; k0 < DM; k0 += 32) {
    const u16* gA = &A[(size_t)(m0 + srow) * DM + k0 + scol];
    const u16* gB = &Bt[(size_t)(n0 + srow) * DM + k0 + scol];
    GLL(gA,           lA + wid * 1024);
    GLL(gA + 16 * DM, lA + wid * 1024 + 512);
    GLL(gB,           lB + wid * 1024);
    GLL(gB + 16 * DM, lB + wid * 1024 + 512);
    __syncthreads();
    bf16x8 af[4], bfr[4];
#pragma unroll
    for (int g = 0; g < 4; ++g) {
      af[g]  = *(const bf16x8*)&lA[(wm + g * 16 + lr) * 32 + lk * 8];
      bfr[g] = *(const bf16x8*)&lB[(wn + g * 16 + lr) * 32 + lk * 8];
    }
#pragma unroll
    for (int mg = 0; mg < 4; ++mg)
#pragma unroll
      for (int ng = 0; ng < 4; ++ng)
        acc[mg][ng] = __builtin_amdgcn_mfma_f32_16x16x32_bf16(af[mg], bfr[ng], acc[mg][ng], 0, 0, 0);
    __syncthreads();
  }

#pragma unroll
  for (int mg = 0; mg < 4; ++mg)
#pragma unroll
    for (int ng = 0; ng < 4; ++ng)
#pragma unroll
      for (int r = 0; r < 4; ++r) {
        int m = m0 + wm + mg * 16 + lk * 4 + r;
        int n = n0 + wn + ng * 16 + lr;
        out[(size_t)m * DM + n] = fast_tanh(acc[mg][ng][r] + bo[n]);
      }
}

// ---- causal flash attention (split-KV<=6, T14, permlane, in-kernel combine)
__global__ __launch_bounds__(256, 3) void attn_kernel(
    const u16* __restrict__ Q, const u16* __restrict__ K,
    const u16* __restrict__ Vt, u16* __restrict__ ctx,
    float* __restrict__ O0, float* __restrict__ O1, float* __restrict__ O2,
    float* __restrict__ L0, float* __restrict__ L1, float* __restrict__ L2,
    int* __restrict__ cnt) {
  __shared__ __attribute__((aligned(16))) char smem[32768];
  __shared__ int lastf;
  const int u = blockIdx.x >> 5;
  const int bh = blockIdx.x & 31;
  int t, lo;
  if (u < 11)       { t = u + 5;  lo = 0; }
  else if (u < 16)  { t = u;      lo = 6; }
  else if (u == 16) { t = 4;      lo = 0; }
  else if (u == 17) { t = 10;     lo = 6; }
  else { int r = u - 18, g = r / 3, c = r % 3;
         if (c == 0)      { t = 3 - g;  lo = 0; }
         else if (c == 1) { t = 9 - g;  lo = 6; }
         else             { t = 15 - g; lo = 12; } }
  const int hi = (lo == 0) ? (t < 5 ? t : 5) : ((lo == 6) ? (t < 11 ? t : 11) : t);

  const int tid = threadIdx.x, wl = tid >> 6, l = tid & 63;
  const int lq = l & 31, hl = l >> 5;
  const int q0 = t * 128 + wl * 32;

  const char* Qb = (const char*)(Q + (size_t)bh * S_ * AD);
  const char* Kb = (const char*)(K + (size_t)bh * S_ * AD);
  const char* Vb = (const char*)(Vt + (size_t)bh * AD * S_);

  int kcst[4], vcst[4], ldso[4];
#pragma unroll
  for (int i = 0; i < 4; ++i) {
    int c = wl * 4 + i;
    int o = c * 1024 + l * 16;
    ldso[i] = c * 1024 + l * 16;
    int row = o >> 8;
    int un = (o & 255) ^ ((row & 15) << 4);
    kcst[i] = (row * 2 + (un >> 7)) * 128 + (un & 127);
    vcst[i] = row * (2 * S_) + un;
  }

  bf16x8 qf[4];
#pragma unroll
  for (int ds = 0; ds < 4; ++ds)
    qf[ds] = *(const bf16x8*)(Qb + (size_t)(q0 + lq) * 128 + ds * 32 + hl * 16);

  f32x16 accO[2] = {};
  float lsum = 0.f;

  {
    bf16x8 kr[4], vr[4];
#pragma unroll
    for (int i = 0; i < 4; ++i) {
      kr[i] = *(const bf16x8*)(Kb + (size_t)lo * 16384 + kcst[i]);
      vr[i] = *(const bf16x8*)(Vb + (size_t)lo * 256  + vcst[i]);
    }
#pragma unroll
    for (int i = 0; i < 4; ++i) {
      *(bf16x8*)(smem + ldso[i])         = kr[i];
      *(bf16x8*)(smem + 16384 + ldso[i]) = vr[i];
    }
  }
  __syncthreads();

  const char* kl = smem;
  const char* vl = smem + 16384;

  auto sblock = [&](int s, bool tri) {
    f32x16 c = {};
    const int kvl = s * 32 + lq;
    const int rp = kvl >> 1, kbit = kvl & 1;
    const int swz = (rp & 15) << 4;
    __builtin_amdgcn_s_setprio(1);
#pragma unroll
    for (int ds = 0; ds < 4; ++ds) {
      bf16x8 a = *(const bf16x8*)(kl + rp * 256 +
                   (((kbit << 7) | (ds * 32 + hl * 16)) ^ swz));
      c = __builtin_amdgcn_mfma_f32_32x32x16_bf16(a, qf[ds], c, 0, 0, 0);
    }
    __builtin_amdgcn_s_setprio(0);

#pragma unroll
    for (int r = 0; r < 16; ++r) {
      float e = __builtin_amdgcn_exp2f(c[r] - SMAX);
      if (tri) {
        int kc = (r & 3) + 8 * (r >> 2) + 4 * hl;
        if (kc > lq) e = 0.f;
      }
      c[r] = e;
      lsum += e;
    }

    unsigned uu[8];
#pragma unroll
    for (int i = 0; i < 8; ++i)
      uu[i] = cvt_pk_bf16(c[2 * i], c[2 * i + 1]);
    unsigned s0a = uu[0], s0b = uu[2];
    unsigned s1a = uu[1], s1b = uu[3];
    unsigned s2a = uu[4], s2b = uu[6];
    unsigned s3a = uu[5], s3b = uu[7];
    asm("v_permlane32_swap_b32 %0, %1" : "+v"(s0a), "+v"(s0b));
    asm("v_permlane32_swap_b32 %0, %1" : "+v"(s1a), "+v"(s1b));
    asm("v_permlane32_swap_b32 %0, %1" : "+v"(s2a), "+v"(s2b));
    asm("v_permlane32_swap_b32 %0, %1" : "+v"(s3a), "+v"(s3b));
    union { unsigned w[4]; bf16x8 v; } c0_, c1_;
    c0_.w[0] = s0a; c0_.w[1] = s1a; c0_.w[2] = s0b; c0_.w[3] = s1b;
    c1_.w[0] = s2a; c1_.w[1] = s3a; c1_.w[2] = s2b; c1_.w[3] = s3b;

    __builtin_amdgcn_s_setprio(1);
#pragma unroll
    for (int d = 0; d < 2; ++d) {
      const int drow = d * 32 + lq;
      const int vswz = (drow & 15) << 4;
      bf16x8 a0 = *(const bf16x8*)(vl + drow * 256 + ((s * 64 + hl * 16) ^ vswz));
      bf16x8 a1 = *(const bf16x8*)(vl + drow * 256 + ((s * 64 + 32 + hl * 16) ^ vswz));
      accO[d] = __builtin_amdgcn_mfma_f32_32x32x16_bf16(a0, c0_.v, accO[d], 0, 0, 0);
      accO[d] = __builtin_amdgcn_mfma_f32_32x32x16_bf16(a1, c1_.v, accO[d], 0, 0, 0);
    }
    __builtin_amdgcn_s_setprio(0);
  };

  for (int kb = lo; kb <= hi; ++kb) {
    bf16x8 krn[4], vrn[4];
    const bool pf = (kb < hi);
    if (pf) {
#pragma unroll
      for (int i = 0; i < 4; ++i) {
        krn[i] = *(const bf16x8*)(Kb + (size_t)(kb + 1) * 16384 + kcst[i]);
        vrn[i] = *(const bf16x8*)(Vb + (size_t)(kb + 1) * 256  + vcst[i]);
      }
    }

    if (kb != t) {
#pragma unroll
      for (int s = 0; s < 4; ++s) sblock(s, false);
    } else {
      for (int s = 0; s < wl; ++s) sblock(s, false);
      sblock(wl, true);
    }

    __syncthreads();
    if (pf) {
#pragma unroll
      for (int i = 0; i < 4; ++i) {
        *(bf16x8*)(smem + ldso[i])         = krn[i];
        *(bf16x8*)(smem + 16384 + ldso[i]) = vrn[i];
      }
    }
    __syncthreads();
  }

  lsum += __shfl_xor(lsum, 32);
  const int q = q0 + lq;

  if (lo == 0 && t < 6) {
    // single-chunk tile: normalize and emit bf16 ctx directly
    const float inv = 1.f / lsum;
    u16* cb_ = ctx + ((size_t)(bh >> 4) * S_ + q) * DM + (bh & 15) * AD;
#pragma unroll
    for (int d = 0; d < 2; ++d)
#pragma unroll
      for (int g = 0; g < 4; ++g) {
        unsigned w0 = cvt_pk_bf16(accO[d][4 * g] * inv,     accO[d][4 * g + 1] * inv);
        unsigned w1 = cvt_pk_bf16(accO[d][4 * g + 2] * inv, accO[d][4 * g + 3] * inv);
        unsigned* dst = (unsigned*)(cb_ + d * 32 + 8 * g + 4 * hl);
        dst[0] = w0; dst[1] = w1;
      }
  } else {
    // multi-chunk: write f32 partial, then split-K arrival combine
    float* Ob; float* Lb;
    if (lo == 0)      { size_t r = (size_t)bh * 1280 + (q - 768);  Ob = O0 + r * 64; Lb = L0 + r; }
    else if (lo == 6) { size_t r = (size_t)bh * 1280 + (q - 768);  Ob = O1 + r * 64; Lb = L1 + r; }
    else              { size_t r = (size_t)bh * 512  + (q - 1536); Ob = O2 + r * 64; Lb = L2 + r; }
#pragma unroll
    for (int d = 0; d < 2; ++d)
#pragma unroll
      for (int g = 0; g < 4; ++g) {
        f32x4 w;
        w[0] = accO[d][4 * g];     w[1] = accO[d][4 * g + 1];
        w[2] = accO[d][4 * g + 2]; w[3] = accO[d][4 * g + 3];
        *(f32x4*)&Ob[d * 32 + 8 * g + 4 * hl] = w;
      }
    if (!hl) *Lb = lsum;

    __threadfence();                      // release: partials visible device-wide
    __syncthreads();
    const int nch = (t >= 12) ? 3 : 2;
    if (tid == 0) {
      int old = atomicAdd(&cnt[bh * 16 + t], 1);
      lastf = (old == nch - 1);
    }
    __syncthreads();
    if (lastf) {
      __threadfence();                    // acquire: invalidate L1/L2 before reads
      const int rq = t * 128 + (tid >> 1);
      const size_t r01 = (size_t)bh * 1280 + (rq - 768);
      float lv = L0[r01] + L1[r01];
      const f32x4* s0 = (const f32x4*)(O0 + r01 * 64 + (tid & 1) * 32);
      const f32x4* s1 = (const f32x4*)(O1 + r01 * 64 + (tid & 1) * 32);
      f32x4 v[8];
#pragma unroll
      for (int i = 0; i < 8; ++i) v[i] = s0[i] + s1[i];
      if (t >= 12) {
        const size_t r2 = (size_t)bh * 512 + (rq - 1536);
        lv += L2[r2];
        const f32x4* s2 = (const f32x4*)(O2 + r2 * 64 + (tid & 1) * 32);
#pragma unroll
        for (int i = 0; i < 8; ++i) v[i] += s2[i];
      }
      const float inv = 1.f / lv;
      unsigned* dst = (unsigned*)(ctx + ((size_t)(bh >> 4) * S_ + rq) * DM +
                                  (bh & 15) * AD + (tid & 1) * 32);
#pragma unroll
      for (int i = 0; i < 8; ++i) {
        dst[2 * i]     = cvt_pk_bf16(v[i][0] * inv, v[i][1] * inv);
        dst[2 * i + 1] = cvt_pk_bf16(v[i][2] * inv, v[i][3] * inv);
      }
      if (tid == 0) cnt[bh * 16 + t] = 0;  // reset for next call
    }
  }
}

extern "C" void kernel_launch(void* const* d_in, const int* in_sizes, int n_in,
                              void* d_out, int out_size, void* d_ws, size_t ws_size,
                              hipStream_t stream) {
  const float* states = (const float*)d_in[0];
  const float* Wq = (const float*)d_in[1];
  const float* bq = (const float*)d_in[2];
  const float* Wk = (const float*)d_in[3];
  const float* bk = (const float*)d_in[4];
  const float* Wv = (const float*)d_in[5];
  const float* bv = (const float*)d_in[6];
  const float* Wo = (const float*)d_in[7];
  const float* bo = (const float*)d_in[8];
  float* out = (float*)d_out;

  u16* sbf = (u16*)d_ws;
  u16* wt  = sbf + ME;
  u16* Qw  = wt + ME;
  u16* Kw  = Qw + ME;
  u16* Vtw = Kw + ME;
  u16* ctx = Vtw + ME;
  float* O0 = (float*)(ctx + ME);
  float* O1 = O0 + (size_t)32 * 1280 * 64;
  int*  cnt = (int*)(O1 + (size_t)32 * 1280 * 64);
  float* O2 = (float*)d_ws;                 // reuses sbf region (dead after qkv)
  float* L0 = O2 + (size_t)32 * 512 * 64;
  float* L1 = L0 + 32 * 1280;
  float* L2 = L1 + 32 * 1280;

  prep<<<dim3(32, 32, 5), dim3(32, 32), 0, stream>>>(Wq, Wk, Wv, Wo, wt, states, sbf, cnt);
  qkv_gemm<<<dim3(8, 32, 3), 256, 0, stream>>>(sbf, wt, bq, bk, bv, Qw, Kw, Vtw);
  attn_kernel<<<960, 256, 0, stream>>>(Qw, Kw, Vtw, ctx, O0, O1, O2, L0, L1, L2, cnt);
  out_gemm<<<dim3(8, 32), 256, 0, stream>>>(ctx, wt + 3 * (size_t)DM * DM, bo, out);
}

// Round 13
// 119.131 us; speedup vs baseline: 2.3376x; 2.3376x over previous
//
#include <hip/hip_runtime.h>
#include <math.h>

typedef unsigned short u16;
typedef __attribute__((ext_vector_type(4))) float f32x4;
typedef __attribute__((ext_vector_type(16))) float f32x16;
typedef __attribute__((ext_vector_type(8))) short bf16x8;

#define B_ 2
#define S_ 2048
#define DM 1024
#define H_ 16
#define AD 64
#define ME 4194304  // elems in one 4096x1024 matrix
#define SC 0.18033688011112042f  // 0.125 * log2(e), folded into Q
#define SMAX 12.0f               // static softmax max: |logit*log2e| <= 11.54

#define GLL(g, s) __builtin_amdgcn_global_load_lds( \
  (const __attribute__((address_space(1))) void*)(g), \
  (__attribute__((address_space(3))) void*)(s), 16, 0, 0)

__device__ inline u16 f2bf(float f) {
  union { float f; unsigned u; } v; v.f = f;
  unsigned r = v.u + 0x7fffu + ((v.u >> 16) & 1u);
  return (u16)(r >> 16);
}

__device__ inline unsigned cvt_pk_bf16(float lo, float hi) {
  unsigned r;
  asm("v_cvt_pk_bf16_f32 %0, %1, %2" : "=v"(r) : "v"(lo), "v"(hi));
  return r;
}

// tanh(x) = 1 - 2/(exp(2x)+1); exp2/rcp HW approx, |err| ~1e-6 << 2e-2 thr
__device__ inline float fast_tanh(float x) {
  float e = __builtin_amdgcn_exp2f(x * 2.885390081777927f);  // exp(2x)
  return 1.f - 2.f * __builtin_amdgcn_rcpf(e + 1.f);
}

// ------- prep: W transpose+cvt (z=0..3), states cvt (z=4) -------------------
__global__ void prep(const float* __restrict__ Wq, const float* __restrict__ Wk,
                     const float* __restrict__ Wv, const float* __restrict__ Wo,
                     u16* __restrict__ Wt, const float* __restrict__ states,
                     u16* __restrict__ sbf) {
  __shared__ float t[32][33];
  const int z = blockIdx.z;
  const int tx = threadIdx.x, ty = threadIdx.y;
  if (z < 4) {
    const float* W = (z == 0) ? Wq : (z == 1) ? Wk : (z == 2) ? Wv : Wo;
    u16* out = Wt + (size_t)z * DM * DM;
    int n0 = blockIdx.x * 32, k0 = blockIdx.y * 32;
    t[ty][tx] = W[(k0 + ty) * DM + n0 + tx];
    __syncthreads();
    out[(n0 + ty) * DM + k0 + tx] = f2bf(t[tx][ty]);
  } else {
    const int lin = blockIdx.y * 32 + blockIdx.x;
    const int tl = ty * 32 + tx;
    const int i = (lin * 1024 + tl) * 4;
    float4 a = *(const float4*)(states + i);
    ushort4 o;
    o.x = f2bf(a.x); o.y = f2bf(a.y); o.z = f2bf(a.z); o.w = f2bf(a.w);
    *(ushort4*)&sbf[i] = o;
  }
}

// ---------------- fused QKV projection GEMM + tanh (R9-proven + T1 swizzle) -
__global__ __launch_bounds__(256) void qkv_gemm(
    const u16* __restrict__ A, const u16* __restrict__ Wt,
    const float* __restrict__ bq, const float* __restrict__ bk, const float* __restrict__ bv,
    u16* __restrict__ Qw, u16* __restrict__ Kw, u16* __restrict__ Vtw) {
  __shared__ __attribute__((aligned(16))) u16 lA[128 * 32];
  __shared__ __attribute__((aligned(16))) u16 lB[128 * 32];
  const int z = blockIdx.z;
  const u16* Bt = Wt + (size_t)z * DM * DM;
  const int lin = blockIdx.y * 8 + blockIdx.x;     // hw dispatch order, x fastest
  const int tile = (lin & 7) * 32 + (lin >> 3);    // XCD-chunked remap
  const int m0 = (tile >> 3) * 128, n0 = (tile & 7) * 128;
  const int tid = threadIdx.x;
  const int wid = tid >> 6, l = tid & 63;
  const int lr = l & 15, lk = l >> 4;
  const int wm = (wid >> 1) * 64, wn = (wid & 1) * 64;
  const int srow = wid * 32 + (l >> 2);
  const int scol = (l & 3) * 8;

  f32x4 acc[4][4] = {};

  for (int k0 = 0; k0 < DM; k0 += 32) {
    const u16* gA = &A[(size_t)(m0 + srow) * DM + k0 + scol];
    const u16* gB = &Bt[(size_t)(n0 + srow) * DM + k0 + scol];
    GLL(gA,           lA + wid * 1024);
    GLL(gA + 16 * DM, lA + wid * 1024 + 512);
    GLL(gB,           lB + wid * 1024);
    GLL(gB + 16 * DM, lB + wid * 1024 + 512);
    __syncthreads();
    bf16x8 af[4], bfr[4];
#pragma unroll
    for (int g = 0; g < 4; ++g) {
      af[g]  = *(const bf16x8*)&lA[(wm + g * 16 + lr) * 32 + lk * 8];
      bfr[g] = *(const bf16x8*)&lB[(wn + g * 16 + lr) * 32 + lk * 8];
    }
#pragma unroll
    for (int mg = 0; mg < 4; ++mg)
#pragma unroll
      for (int ng = 0; ng < 4; ++ng)
        acc[mg][ng] = __builtin_amdgcn_mfma_f32_16x16x32_bf16(af[mg], bfr[ng], acc[mg][ng], 0, 0, 0);
    __syncthreads();
  }

  const float* bias = (z == 0) ? bq : (z == 1) ? bk : bv;
#pragma unroll
  for (int mg = 0; mg < 4; ++mg)
#pragma unroll
    for (int ng = 0; ng < 4; ++ng)
#pragma unroll
      for (int r = 0; r < 4; ++r) {
        int m = m0 + wm + mg * 16 + lk * 4 + r;
        int n = n0 + wn + ng * 16 + lr;
        float v = fast_tanh(acc[mg][ng][r] + bias[n]);
        if (z == 0) v *= SC;  // fold softmax scale into Q
        u16 h16 = f2bf(v);
        int bb = m >> 11, s = m & 2047, hh = n >> 6, d = n & 63;
        if (z == 2) Vtw[((size_t)(bb * H_ + hh) * AD + d) * S_ + s] = h16;
        else ((z == 0) ? Qw : Kw)[((size_t)(bb * H_ + hh) * S_ + s) * AD + d] = h16;
      }
}

// ---------------- output projection GEMM + tanh (R9-proven + T1 swizzle) ----
__global__ __launch_bounds__(256) void out_gemm(
    const u16* __restrict__ A, const u16* __restrict__ Bt,
    const float* __restrict__ bo, float* __restrict__ out) {
  __shared__ __attribute__((aligned(16))) u16 lA[128 * 32];
  __shared__ __attribute__((aligned(16))) u16 lB[128 * 32];
  const int lin = blockIdx.y * 8 + blockIdx.x;
  const int tile = (lin & 7) * 32 + (lin >> 3);
  const int m0 = (tile >> 3) * 128, n0 = (tile & 7) * 128;
  const int tid = threadIdx.x;
  const int wid = tid >> 6, l = tid & 63;
  const int lr = l & 15, lk = l >> 4;
  const int wm = (wid >> 1) * 64, wn = (wid & 1) * 64;
  const int srow = wid * 32 + (l >> 2);
  const int scol = (l & 3) * 8;

  f32x4 acc[4][4] = {};

  for (int k0 = 0; k0 < DM; k0 += 32) {
    const u16* gA = &A[(size_t)(m0 + srow) * DM + k0 + scol];
    const u16* gB = &Bt[(size_t)(n0 + srow) * DM + k0 + scol];
    GLL(gA,           lA + wid * 1024);
    GLL(gA + 16 * DM, lA + wid * 1024 + 512);
    GLL(gB,           lB + wid * 1024);
    GLL(gB + 16 * DM, lB + wid * 1024 + 512);
    __syncthreads();
    bf16x8 af[4], bfr[4];
#pragma unroll
    for (int g = 0; g < 4; ++g) {
      af[g]  = *(const bf16x8*)&lA[(wm + g * 16 + lr) * 32 + lk * 8];
      bfr[g] = *(const bf16x8*)&lB[(wn + g * 16 + lr) * 32 + lk * 8];
    }
#pragma unroll
    for (int mg = 0; mg < 4; ++mg)
#pragma unroll
      for (int ng = 0; ng < 4; ++ng)
        acc[mg][ng] = __builtin_amdgcn_mfma_f32_16x16x32_bf16(af[mg], bfr[ng], acc[mg][ng], 0, 0, 0);
    __syncthreads();
  }

#pragma unroll
  for (int mg = 0; mg < 4; ++mg)
#pragma unroll
    for (int ng = 0; ng < 4; ++ng)
#pragma unroll
      for (int r = 0; r < 4; ++r) {
        int m = m0 + wm + mg * 16 + lk * 4 + r;
        int n = n0 + wn + ng * 16 + lr;
        out[(size_t)m * DM + n] = fast_tanh(acc[mg][ng][r] + bo[n]);
      }
}

// ---------------- causal flash attention (split-KV<=6, T14, permlane) -------
__global__ __launch_bounds__(256, 3) void attn_kernel(
    const u16* __restrict__ Q, const u16* __restrict__ K,
    const u16* __restrict__ Vt, u16* __restrict__ ctx,
    float* __restrict__ O0, float* __restrict__ O1, float* __restrict__ O2,
    float* __restrict__ L0, float* __restrict__ L1, float* __restrict__ L2) {
  __shared__ __attribute__((aligned(16))) char smem[32768];
  const int u = blockIdx.x >> 5;
  const int bh = blockIdx.x & 31;
  int t, lo;
  if (u < 11)       { t = u + 5;  lo = 0; }
  else if (u < 16)  { t = u;      lo = 6; }
  else if (u == 16) { t = 4;      lo = 0; }
  else if (u == 17) { t = 10;     lo = 6; }
  else { int r = u - 18, g = r / 3, c = r % 3;
         if (c == 0)      { t = 3 - g;  lo = 0; }
         else if (c == 1) { t = 9 - g;  lo = 6; }
         else             { t = 15 - g; lo = 12; } }
  const int hi = (lo == 0) ? (t < 5 ? t : 5) : ((lo == 6) ? (t < 11 ? t : 11) : t);

  const int tid = threadIdx.x, wl = tid >> 6, l = tid & 63;
  const int lq = l & 31, hl = l >> 5;
  const int q0 = t * 128 + wl * 32;

  const char* Qb = (const char*)(Q + (size_t)bh * S_ * AD);
  const char* Kb = (const char*)(K + (size_t)bh * S_ * AD);
  const char* Vb = (const char*)(Vt + (size_t)bh * AD * S_);

  int kcst[4], vcst[4], ldso[4];
#pragma unroll
  for (int i = 0; i < 4; ++i) {
    int c = wl * 4 + i;
    int o = c * 1024 + l * 16;
    ldso[i] = c * 1024 + l * 16;
    int row = o >> 8;
    int un = (o & 255) ^ ((row & 15) << 4);
    kcst[i] = (row * 2 + (un >> 7)) * 128 + (un & 127);
    vcst[i] = row * (2 * S_) + un;
  }

  bf16x8 qf[4];
#pragma unroll
  for (int ds = 0; ds < 4; ++ds)
    qf[ds] = *(const bf16x8*)(Qb + (size_t)(q0 + lq) * 128 + ds * 32 + hl * 16);

  f32x16 accO[2] = {};
  float lsum = 0.f;

  {
    bf16x8 kr[4], vr[4];
#pragma unroll
    for (int i = 0; i < 4; ++i) {
      kr[i] = *(const bf16x8*)(Kb + (size_t)lo * 16384 + kcst[i]);
      vr[i] = *(const bf16x8*)(Vb + (size_t)lo * 256  + vcst[i]);
    }
#pragma unroll
    for (int i = 0; i < 4; ++i) {
      *(bf16x8*)(smem + ldso[i])         = kr[i];
      *(bf16x8*)(smem + 16384 + ldso[i]) = vr[i];
    }
  }
  __syncthreads();

  const char* kl = smem;
  const char* vl = smem + 16384;

  auto sblock = [&](int s, bool tri) {
    f32x16 c = {};
    const int kvl = s * 32 + lq;
    const int rp = kvl >> 1, kbit = kvl & 1;
    const int swz = (rp & 15) << 4;
    __builtin_amdgcn_s_setprio(1);
#pragma unroll
    for (int ds = 0; ds < 4; ++ds) {
      bf16x8 a = *(const bf16x8*)(kl + rp * 256 +
                   (((kbit << 7) | (ds * 32 + hl * 16)) ^ swz));
      c = __builtin_amdgcn_mfma_f32_32x32x16_bf16(a, qf[ds], c, 0, 0, 0);
    }
    __builtin_amdgcn_s_setprio(0);

#pragma unroll
    for (int r = 0; r < 16; ++r) {
      float e = __builtin_amdgcn_exp2f(c[r] - SMAX);
      if (tri) {
        int kc = (r & 3) + 8 * (r >> 2) + 4 * hl;
        if (kc > lq) e = 0.f;
      }
      c[r] = e;
      lsum += e;
    }

    unsigned uu[8];
#pragma unroll
    for (int i = 0; i < 8; ++i)
      uu[i] = cvt_pk_bf16(c[2 * i], c[2 * i + 1]);
    unsigned s0a = uu[0], s0b = uu[2];
    unsigned s1a = uu[1], s1b = uu[3];
    unsigned s2a = uu[4], s2b = uu[6];
    unsigned s3a = uu[5], s3b = uu[7];
    asm("v_permlane32_swap_b32 %0, %1" : "+v"(s0a), "+v"(s0b));
    asm("v_permlane32_swap_b32 %0, %1" : "+v"(s1a), "+v"(s1b));
    asm("v_permlane32_swap_b32 %0, %1" : "+v"(s2a), "+v"(s2b));
    asm("v_permlane32_swap_b32 %0, %1" : "+v"(s3a), "+v"(s3b));
    union { unsigned w[4]; bf16x8 v; } c0_, c1_;
    c0_.w[0] = s0a; c0_.w[1] = s1a; c0_.w[2] = s0b; c0_.w[3] = s1b;
    c1_.w[0] = s2a; c1_.w[1] = s3a; c1_.w[2] = s2b; c1_.w[3] = s3b;

    __builtin_amdgcn_s_setprio(1);
#pragma unroll
    for (int d = 0; d < 2; ++d) {
      const int drow = d * 32 + lq;
      const int vswz = (drow & 15) << 4;
      bf16x8 a0 = *(const bf16x8*)(vl + drow * 256 + ((s * 64 + hl * 16) ^ vswz));
      bf16x8 a1 = *(const bf16x8*)(vl + drow * 256 + ((s * 64 + 32 + hl * 16) ^ vswz));
      accO[d] = __builtin_amdgcn_mfma_f32_32x32x16_bf16(a0, c0_.v, accO[d], 0, 0, 0);
      accO[d] = __builtin_amdgcn_mfma_f32_32x32x16_bf16(a1, c1_.v, accO[d], 0, 0, 0);
    }
    __builtin_amdgcn_s_setprio(0);
  };

  for (int kb = lo; kb <= hi; ++kb) {
    bf16x8 krn[4], vrn[4];
    const bool pf = (kb < hi);
    if (pf) {
#pragma unroll
      for (int i = 0; i < 4; ++i) {
        krn[i] = *(const bf16x8*)(Kb + (size_t)(kb + 1) * 16384 + kcst[i]);
        vrn[i] = *(const bf16x8*)(Vb + (size_t)(kb + 1) * 256  + vcst[i]);
      }
    }

    if (kb != t) {
#pragma unroll
      for (int s = 0; s < 4; ++s) sblock(s, false);
    } else {
      for (int s = 0; s < wl; ++s) sblock(s, false);
      sblock(wl, true);
    }

    __syncthreads();
    if (pf) {
#pragma unroll
      for (int i = 0; i < 4; ++i) {
        *(bf16x8*)(smem + ldso[i])         = krn[i];
        *(bf16x8*)(smem + 16384 + ldso[i]) = vrn[i];
      }
    }
    __syncthreads();
  }

  lsum += __shfl_xor(lsum, 32);
  const int q = q0 + lq;

  if (lo == 0 && t < 6) {
    const float inv = 1.f / lsum;
    u16* cb_ = ctx + ((size_t)(bh >> 4) * S_ + q) * DM + (bh & 15) * AD;
#pragma unroll
    for (int d = 0; d < 2; ++d)
#pragma unroll
      for (int g = 0; g < 4; ++g) {
        unsigned w0 = cvt_pk_bf16(accO[d][4 * g] * inv,     accO[d][4 * g + 1] * inv);
        unsigned w1 = cvt_pk_bf16(accO[d][4 * g + 2] * inv, accO[d][4 * g + 3] * inv);
        unsigned* dst = (unsigned*)(cb_ + d * 32 + 8 * g + 4 * hl);
        dst[0] = w0; dst[1] = w1;
      }
  } else {
    float* Ob; float* Lb;
    if (lo == 0)      { size_t r = (size_t)bh * 1280 + (q - 768);  Ob = O0 + r * 64; Lb = L0 + r; }
    else if (lo == 6) { size_t r = (size_t)bh * 1280 + (q - 768);  Ob = O1 + r * 64; Lb = L1 + r; }
    else              { size_t r = (size_t)bh * 512  + (q - 1536); Ob = O2 + r * 64; Lb = L2 + r; }
#pragma unroll
    for (int d = 0; d < 2; ++d)
#pragma unroll
      for (int g = 0; g < 4; ++g) {
        f32x4 w;
        w[0] = accO[d][4 * g];     w[1] = accO[d][4 * g + 1];
        w[2] = accO[d][4 * g + 2]; w[3] = accO[d][4 * g + 3];
        *(f32x4*)&Ob[d * 32 + 8 * g + 4 * hl] = w;
      }
    if (!hl) *Lb = lsum;
  }
}

// ---------------- combine partials (rows q>=768 only), emit bf16 ctx --------
__global__ __launch_bounds__(256) void attn_norm(
    const float* __restrict__ O0, const float* __restrict__ O1,
    const float* __restrict__ O2, const float* __restrict__ L0,
    const float* __restrict__ L1, const float* __restrict__ L2,
    u16* __restrict__ ctx) {
  const int tid = threadIdx.x;
  const int rowl = blockIdx.x * 64 + (tid >> 2);  // bh*1280 + (q-768)
  const int sub = tid & 3;
  const int bh = rowl / 1280, qr = rowl - bh * 1280;
  const int q = 768 + qr;
  float lv = L0[rowl] + L1[rowl];
  const f32x4* p0 = (const f32x4*)(O0 + (size_t)rowl * 64 + sub * 16);
  const f32x4* p1 = (const f32x4*)(O1 + (size_t)rowl * 64 + sub * 16);
  f32x4 v0 = p0[0] + p1[0], v1 = p0[1] + p1[1];
  f32x4 v2 = p0[2] + p1[2], v3 = p0[3] + p1[3];
  if (q >= 1536) {
    size_t r2 = (size_t)bh * 512 + (q - 1536);
    lv += L2[r2];
    const f32x4* p2 = (const f32x4*)(O2 + r2 * 64 + sub * 16);
    v0 += p2[0]; v1 += p2[1]; v2 += p2[2]; v3 += p2[3];
  }
  const float inv = 1.f / lv;
  const int b = bh >> 4, h = bh & 15;
  unsigned w[8];
  w[0] = cvt_pk_bf16(v0[0] * inv, v0[1] * inv);
  w[1] = cvt_pk_bf16(v0[2] * inv, v0[3] * inv);
  w[2] = cvt_pk_bf16(v1[0] * inv, v1[1] * inv);
  w[3] = cvt_pk_bf16(v1[2] * inv, v1[3] * inv);
  w[4] = cvt_pk_bf16(v2[0] * inv, v2[1] * inv);
  w[5] = cvt_pk_bf16(v2[2] * inv, v2[3] * inv);
  w[6] = cvt_pk_bf16(v3[0] * inv, v3[1] * inv);
  w[7] = cvt_pk_bf16(v3[2] * inv, v3[3] * inv);
  unsigned* dst = (unsigned*)(ctx + ((size_t)b * S_ + q) * DM + h * AD + sub * 16);
#pragma unroll
  for (int i = 0; i < 8; ++i) dst[i] = w[i];
}

extern "C" void kernel_launch(void* const* d_in, const int* in_sizes, int n_in,
                              void* d_out, int out_size, void* d_ws, size_t ws_size,
                              hipStream_t stream) {
  const float* states = (const float*)d_in[0];
  const float* Wq = (const float*)d_in[1];
  const float* bq = (const float*)d_in[2];
  const float* Wk = (const float*)d_in[3];
  const float* bk = (const float*)d_in[4];
  const float* Wv = (const float*)d_in[5];
  const float* bv = (const float*)d_in[6];
  const float* Wo = (const float*)d_in[7];
  const float* bo = (const float*)d_in[8];
  float* out = (float*)d_out;

  u16* sbf = (u16*)d_ws;
  u16* wt  = sbf + ME;
  u16* Qw  = wt + ME;
  u16* Kw  = Qw + ME;
  u16* Vtw = Kw + ME;
  u16* ctx = Vtw + ME;
  float* O0 = (float*)(ctx + ME);
  float* O1 = O0 + (size_t)32 * 1280 * 64;
  float* O2 = (float*)d_ws;                 // reuses sbf region (dead after qkv)
  float* L0 = O2 + (size_t)32 * 512 * 64;
  float* L1 = L0 + 32 * 1280;
  float* L2 = L1 + 32 * 1280;

  prep<<<dim3(32, 32, 5), dim3(32, 32), 0, stream>>>(Wq, Wk, Wv, Wo, wt, states, sbf);
  qkv_gemm<<<dim3(8, 32, 3), 256, 0, stream>>>(sbf, wt, bq, bk, bv, Qw, Kw, Vtw);
  attn_kernel<<<960, 256, 0, stream>>>(Qw, Kw, Vtw, ctx, O0, O1, O2, L0, L1, L2);
  attn_norm<<<640, 256, 0, stream>>>(O0, O1, O2, L0, L1, L2, ctx);
  out_gemm<<<dim3(8, 32), 256, 0, stream>>>(ctx, wt + 3 * (size_t)DM * DM, bo, out);
}